// Round 1
// baseline (237.902 us; speedup 1.0000x reference)
//
#include <hip/hip_runtime.h>

#define SEG 256
#define SMOOTH_K 9
#define BASE_AMP 0.08f
#define L 4096
#define ROW (2 * L)          // floats per batch row
#define VEC_PER_THREAD 8     // 256 threads * 8 * float4 = 8192 floats

// ---------------------------------------------------------------------------
// Kernel 1: effective pattern -> d_ws (512 floats: [2][256])
// ---------------------------------------------------------------------------
__global__ __launch_bounds__(256) void pattern_kernel(
    const float* __restrict__ pi, const float* __restrict__ pq,
    float* __restrict__ pat_out) {
    __shared__ float wsum0[4], wsum1[4], wsq[4];

    const int i = threadIdx.x;            // 0..255 (position)
    // 'same' box smooth, zero padding, always /9 (count_include_pad=True)
    float v0 = 0.f, v1 = 0.f;
    #pragma unroll
    for (int j = -(SMOOTH_K / 2); j <= SMOOTH_K / 2; ++j) {
        int k = i + j;
        if (k >= 0 && k < SEG) { v0 += pi[k]; v1 += pq[k]; }
    }
    v0 *= (1.0f / SMOOTH_K);
    v1 *= (1.0f / SMOOTH_K);

    // per-channel mean over 256
    float s0 = v0, s1 = v1;
    #pragma unroll
    for (int off = 32; off; off >>= 1) {
        s0 += __shfl_down(s0, off);
        s1 += __shfl_down(s1, off);
    }
    const int wid = i >> 6, lane = i & 63;
    if (lane == 0) { wsum0[wid] = s0; wsum1[wid] = s1; }
    __syncthreads();
    const float m0 = (wsum0[0] + wsum0[1] + wsum0[2] + wsum0[3]) * (1.0f / SEG);
    const float m1 = (wsum1[0] + wsum1[1] + wsum1[2] + wsum1[3]) * (1.0f / SEG);
    const float d0 = v0 - m0;
    const float d1 = v1 - m1;

    // global mean of squares over 512
    float q = d0 * d0 + d1 * d1;
    #pragma unroll
    for (int off = 32; off; off >>= 1) q += __shfl_down(q, off);
    if (lane == 0) wsq[wid] = q;
    __syncthreads();
    const float msq = (wsq[0] + wsq[1] + wsq[2] + wsq[3]) * (1.0f / (2 * SEG));
    const float scale = BASE_AMP / sqrtf(msq + 1e-8f);

    pat_out[i]       = d0 * scale;
    pat_out[SEG + i] = d1 * scale;
}

// ---------------------------------------------------------------------------
// Kernel 2: one block per batch row. Read row once into registers, block
// reduce sum-of-squares -> amp, write out = x (+ amp*pat on the slice).
// ---------------------------------------------------------------------------
__global__ __launch_bounds__(256) void apply_kernel(
    const float* __restrict__ x, const int* __restrict__ starts,
    const float* __restrict__ pat, float* __restrict__ out) {
    const int b = blockIdx.x;
    const int t = threadIdx.x;

    const float4* __restrict__ xr =
        reinterpret_cast<const float4*>(x + (size_t)b * ROW);
    float4* __restrict__ outr = reinterpret_cast<float4*>(out + (size_t)b * ROW);

    __shared__ float spat[2 * SEG];
    __shared__ float wred[4];
    spat[t]       = pat[t];
    spat[t + SEG] = pat[t + SEG];

    // load entire row into registers (coalesced float4), accumulate squares
    float4 v[VEC_PER_THREAD];
    float ssq = 0.f;
    #pragma unroll
    for (int k = 0; k < VEC_PER_THREAD; ++k) {
        v[k] = xr[t + k * 256];
        ssq += v[k].x * v[k].x + v[k].y * v[k].y + v[k].z * v[k].z +
               v[k].w * v[k].w;
    }

    // block reduce (wave shuffle + LDS across the 4 waves)
    #pragma unroll
    for (int off = 32; off; off >>= 1) ssq += __shfl_down(ssq, off);
    const int wid = t >> 6, lane = t & 63;
    if (lane == 0) wred[wid] = ssq;
    __syncthreads();   // also covers spat visibility
    const float tot = wred[0] + wred[1] + wred[2] + wred[3];
    const float amp = sqrtf(tot * (1.0f / ROW) + 1e-12f);

    const int s = starts[b];

    #pragma unroll
    for (int k = 0; k < VEC_PER_THREAD; ++k) {
        const int fi = (t + k * 256) << 2;   // float offset within row
        const int c  = fi >> 12;             // channel (0 or 1)
        const int l  = fi & (L - 1);         // time index of .x
        const float* __restrict__ pc = spat + c * SEG;
        float4 o = v[k];
        const int r = l - s;                 // relative pos of .x in segment
        if (r >= 0     && r < SEG)     o.x += amp * pc[r];
        if (r + 1 >= 0 && r + 1 < SEG) o.y += amp * pc[r + 1];
        if (r + 2 >= 0 && r + 2 < SEG) o.z += amp * pc[r + 2];
        if (r + 3 >= 0 && r + 3 < SEG) o.w += amp * pc[r + 3];
        outr[t + k * 256] = o;
    }
}

// ---------------------------------------------------------------------------
extern "C" void kernel_launch(void* const* d_in, const int* in_sizes, int n_in,
                              void* d_out, int out_size, void* d_ws,
                              size_t ws_size, hipStream_t stream) {
    const float* x      = (const float*)d_in[0];
    const float* pi     = (const float*)d_in[1];
    const float* pq     = (const float*)d_in[2];
    const int*   starts = (const int*)d_in[3];
    float* out = (float*)d_out;
    float* pat = (float*)d_ws;   // 512 floats

    const int B = in_sizes[0] / ROW;   // 4096

    pattern_kernel<<<1, 256, 0, stream>>>(pi, pq, pat);
    apply_kernel<<<B, 256, 0, stream>>>(x, starts, pat, out);
}